// Round 3
// baseline (14.049 us; speedup 1.0000x reference)
//
#include <hip/hip_runtime.h>

// velocity[b,p,:] = 1/(2pi) * sum_v tau_v * (1-exp(-sq/sig^2))/sq * (d1, -d0)
// vf = (4,256,4) [y,x,tau,sig];  pts/out = (4,16384,2)

constexpr int NV = 256;
constexpr int PPB = 16384;
constexpr float INV_2PI = 0.15915494309189535f;
constexpr float LOG2E = 1.4426950408889634f;

#if defined(__has_builtin)
#if __has_builtin(__builtin_amdgcn_exp2f)
#define USE_RAW_EXP2 1
#endif
#endif

__global__ __launch_bounds__(256) void vortex_vel_kernel(
    const float4* __restrict__ vf,   // (4,256) of {y,x,tau,sig}
    const float2* __restrict__ pts,  // (4*16384)
    float* __restrict__ out)         // (4*16384*2)
{
    const int b     = blockIdx.x >> 8;           // 256 blocks per batch
    const int pbase = (blockIdx.x & 255) << 6;   // 64 points per block
    const int t     = threadIdx.x;
    const int lane  = t & 63;
    // wave id = vortex chunk (scalarized so vortex loads are s_load via K$)
    const int chunk = __builtin_amdgcn_readfirstlane(t >> 6);

    const float2 p = pts[b * PPB + pbase + lane];
    const float4* vfc = vf + b * NV + chunk * 64;

    // Per-lane hoist: lane k holds -log2e/sigma^2 (or -1/sigma^2 for the
    // __expf fallback) for vortex chunk*64+k. One rcp per 64 loop iters.
    const float sigl = vfc[lane].w;
#ifdef USE_RAW_EXP2
    const float visig = -LOG2E * __builtin_amdgcn_rcpf(sigl * sigl);
#else
    const float visig = -__builtin_amdgcn_rcpf(sigl * sigl);
#endif

    float v0 = 0.0f, v1 = 0.0f;
    #pragma unroll
    for (int k = 0; k < 64; ++k) {
        const float4 v = vfc[k];                 // wave-uniform -> s_load_dwordx4
        // broadcast lane k's precomputed scale (immediate-lane v_readlane)
        const float isig = __int_as_float(
            __builtin_amdgcn_readlane(__float_as_int(visig), k));
        const float d0 = p.x - v.x;
        const float d1 = p.y - v.y;
        const float sq = fmaf(d0, d0, d1 * d1);
#ifdef USE_RAW_EXP2
        const float e  = __builtin_amdgcn_exp2f(sq * isig);   // exp(-sq/sig^2)
#else
        const float e  = __expf(sq * isig);
#endif
        const float r  = __builtin_amdgcn_rcpf(sq);
        const float w  = fmaf(-e, r, r) * v.z;   // tau * (1-e) / sq
        v0 = fmaf(w, d1, v0);
        v1 = fmaf(-w, d0, v1);
    }

    // Reduce the 4 vortex-chunk partials per point (conflict-free layout).
    __shared__ float red[4][64][2];
    red[chunk][lane][0] = v0;
    red[chunk][lane][1] = v1;
    __syncthreads();

    if (t < 128) {
        const int pt = t >> 1, c = t & 1;
        const float s = red[0][pt][c] + red[1][pt][c]
                      + red[2][pt][c] + red[3][pt][c];
        out[(b * PPB + pbase) * 2 + t] = s * INV_2PI;
    }
}

extern "C" void kernel_launch(void* const* d_in, const int* in_sizes, int n_in,
                              void* d_out, int out_size, void* d_ws, size_t ws_size,
                              hipStream_t stream) {
    const float4* vf  = (const float4*)d_in[0];  // (4,256,4)
    const float2* pts = (const float2*)d_in[1];  // (4,128,128,2)
    float* out = (float*)d_out;

    dim3 grid(1024);   // 4 batches * 256 point-blocks (64 pts, 4 vortex chunks)
    dim3 block(256);
    vortex_vel_kernel<<<grid, block, 0, stream>>>(vf, pts, out);
}

// Round 4
// 13.132 us; speedup vs baseline: 1.0698x; 1.0698x over previous
//
#include <hip/hip_runtime.h>

// velocity[b,p,:] = 1/(2pi) * sum_v tau_v * (1-exp(-sq/sig^2))/sq * (d1, -d0)
// vf = (4,256,4) [y,x,tau,sig];  pts/out = (4,16384,2)

constexpr int NV = 256;
constexpr int PPB = 16384;
constexpr float INV_2PI = 0.15915494309189535f;
constexpr float LOG2E = 1.4426950408889634f;

#if defined(__has_builtin)
#if __has_builtin(__builtin_amdgcn_exp2f)
#define USE_RAW_EXP2 1
#endif
#endif

__global__ __launch_bounds__(256) void vortex_vel_kernel(
    const float4* __restrict__ vf,   // (4,256) of {y,x,tau,sig}
    const float2* __restrict__ pts,  // (4*16384)
    float* __restrict__ out)         // (4*16384*2)
{
    const int b     = blockIdx.x >> 8;           // 256 blocks per batch
    const int pbase = (blockIdx.x & 255) << 6;   // 64 points per block
    const int t     = threadIdx.x;
    const int lane  = t & 63;
    // wave id = vortex chunk (scalarized so vortex loads are s_load via K$)
    const int chunk = __builtin_amdgcn_readfirstlane(t >> 6);

    const float2 p = pts[b * PPB + pbase + lane];
    const float4* vfc = vf + b * NV + chunk * 64;

    // Per-lane hoist: lane k holds -log2e/sigma^2 for vortex chunk*64+k.
    // One rcp per 64 loop iters; broadcast per-iter with a runtime readlane
    // (compatible with partial unroll, unlike immediate-lane indexing).
    const float sigl = vfc[lane].w;
#ifdef USE_RAW_EXP2
    const float visig = -LOG2E * __builtin_amdgcn_rcpf(sigl * sigl);
#else
    const float visig = -__builtin_amdgcn_rcpf(sigl * sigl);
#endif
    const int visig_i = __float_as_int(visig);

    float v0 = 0.0f, v1 = 0.0f;
    #pragma unroll 8
    for (int k = 0; k < 64; ++k) {
        const float4 v = vfc[k];                 // wave-uniform -> s_load_dwordx4
        const float isig = __int_as_float(__builtin_amdgcn_readlane(visig_i, k));
        const float d0 = p.x - v.x;
        const float d1 = p.y - v.y;
        const float sq = fmaf(d0, d0, d1 * d1);
#ifdef USE_RAW_EXP2
        const float e  = __builtin_amdgcn_exp2f(sq * isig);   // exp(-sq/sig^2)
#else
        const float e  = __expf(sq * isig);
#endif
        const float r  = __builtin_amdgcn_rcpf(sq);
        const float w  = fmaf(-e, r, r) * v.z;   // tau * (1-e) / sq
        v0 = fmaf(w, d1, v0);
        v1 = fmaf(-w, d0, v1);
    }

    // Reduce the 4 vortex-chunk partials per point (conflict-free layout).
    __shared__ float red[4][64][2];
    red[chunk][lane][0] = v0;
    red[chunk][lane][1] = v1;
    __syncthreads();

    if (t < 128) {
        const int pt = t >> 1, c = t & 1;
        const float s = red[0][pt][c] + red[1][pt][c]
                      + red[2][pt][c] + red[3][pt][c];
        out[(b * PPB + pbase) * 2 + t] = s * INV_2PI;
    }
}

extern "C" void kernel_launch(void* const* d_in, const int* in_sizes, int n_in,
                              void* d_out, int out_size, void* d_ws, size_t ws_size,
                              hipStream_t stream) {
    const float4* vf  = (const float4*)d_in[0];  // (4,256,4)
    const float2* pts = (const float2*)d_in[1];  // (4,128,128,2)
    float* out = (float*)d_out;

    dim3 grid(1024);   // 4 batches * 256 point-blocks (64 pts, 4 vortex chunks)
    dim3 block(256);
    vortex_vel_kernel<<<grid, block, 0, stream>>>(vf, pts, out);
}